// Round 4
// baseline (248.405 us; speedup 1.0000x reference)
//
#include <hip/hip_runtime.h>

#define BB 16
#define FF 256
#define TT 8192
#define F_CHUNK 8
#define THREADS 256
#define PT 8   // consecutive floats per thread along t

typedef float f32x4 __attribute__((ext_vector_type(4)));

__device__ __forceinline__ unsigned sbit(float x) { return __float_as_uint(x) >> 31u; }

struct Raw { float4 a, b; float e; };
struct Row { float v[PT]; unsigned s; };   // s bits 0..8 = signbits of e0..e7, e8(neighbor)

__global__ __launch_bounds__(THREADS, 8) void sst_kernel(const float* __restrict__ in,
                                                         float* __restrict__ out) {
    const int t0   = blockIdx.x * (THREADS * PT) + threadIdx.x * PT;
    const int fs   = blockIdx.y * F_CHUNK;
    const int b    = blockIdx.z;
    const int lane = threadIdx.x & 63;
    const bool tail = (t0 + PT >= TT);   // thread owning t = TT-1 (the pad column)

    const float* src = in  + (size_t)b * FF * TT + t0;
    float*       dst = out + (size_t)b * FF * TT + t0;

    auto load_raw = [&](int f) {
        Raw r;
        const float* p = src + (size_t)f * TT;
        r.a = *reinterpret_cast<const float4*>(p);
        r.b = *reinterpret_cast<const float4*>(p + 4);
        // sign source for element t0+8: next lane's a.x, except lane 63 -> scalar
        r.e = (lane == 63 && !tail) ? p[PT] : 0.0f;
        return r;
    };
    auto finish = [&](const Raw& r) {
        Row w;
        float nxt = __shfl_down(r.a.x, 1, 64);
        if (lane == 63) nxt = r.e;
        unsigned s = sbit(r.a.x)        | (sbit(r.a.y) << 1) | (sbit(r.a.z) << 2)
                   | (sbit(r.a.w) << 3) | (sbit(r.b.x) << 4) | (sbit(r.b.y) << 5)
                   | (sbit(r.b.z) << 6) | (sbit(r.b.w) << 7) | (sbit(nxt)   << 8);
        if (tail) s = (s & 0xFFu) | ((s & 0x80u) << 1);   // force adj(TT-1) = 0
        w.s = s;
        w.v[0] = r.a.x; w.v[1] = r.a.y; w.v[2] = r.a.z; w.v[3] = r.a.w;
        w.v[4] = r.b.x; w.v[5] = r.b.y; w.v[6] = r.b.z; w.v[7] = r.b.w;
        return w;
    };

    Row rprev, rcur, rnext;
    Raw rn, rn2;

    // ---- prologue ----
    if (fs == 0) {
        rprev.s = 0u;                       // adj never +1 -> no prev contribution
        #pragma unroll
        for (int j = 0; j < PT; ++j) rprev.v[j] = 0.f;
    } else {
        rprev = finish(load_raw(fs - 1));
    }
    rcur = finish(load_raw(fs));
    rn = load_raw(fs + 1);                  // fs+1 <= FF-7, always valid

    #pragma unroll
    for (int i = 0; i < F_CHUNK; ++i) {
        const int g = fs + i;

        // prefetch row g+2 before consuming row g+1
        if (i + 2 <= F_CHUNK && g + 2 < FF) rn2 = load_raw(g + 2);

        if (g + 1 < FF) {
            rnext = finish(rn);
        } else {
            rnext.s = 0u;                   // adj never -1 -> no next contribution
            #pragma unroll
            for (int j = 0; j < PT; ++j) rnext.v[j] = 0.f;
        }

        const bool isFirst = (g == 0);
        const bool isLast  = (g == FF - 1);

        // adj code from 2 sign bits: x=(s>>j)&3; x==2 -> adj=+1, x==1 -> adj=-1,
        // x==0||x==3 -> adj=0
        float r[PT];
        #pragma unroll
        for (int j = 0; j < PT; ++j) {
            const unsigned xp = (rprev.s >> j) & 3u;
            const unsigned xc = (rcur.s  >> j) & 3u;
            const unsigned xn = (rnext.s >> j) & 3u;
            const bool bc = (xc == 0u) || (xc == 3u)
                          || (isFirst && xc == 1u)    // clip k=-1 -> 0
                          || (isLast  && xc == 2u);   // clip k=FF -> FF-1
            r[j] = ((xp == 2u) ? rprev.v[j] : 0.f)
                 + (bc          ? rcur.v[j]  : 0.f)
                 + ((xn == 1u)  ? rnext.v[j] : 0.f);
        }

        f32x4 o0 = { r[0], r[1], r[2], r[3] };
        f32x4 o1 = { r[4], r[5], r[6], r[7] };
        f32x4* dp = reinterpret_cast<f32x4*>(dst + (size_t)g * TT);
        __builtin_nontemporal_store(o0, dp);
        __builtin_nontemporal_store(o1, dp + 1);

        rprev = rcur; rcur = rnext; rn = rn2;
    }
}

extern "C" void kernel_launch(void* const* d_in, const int* in_sizes, int n_in,
                              void* d_out, int out_size, void* d_ws, size_t ws_size,
                              hipStream_t stream) {
    const float* in  = (const float*)d_in[0];
    float*       out = (float*)d_out;
    // grid: (t-blocks, f-chunks, batch) = (4, 32, 16) -> 2048 blocks, 8 blocks/CU
    dim3 grid(TT / (THREADS * PT), FF / F_CHUNK, BB);
    sst_kernel<<<grid, THREADS, 0, stream>>>(in, out);
}